// Round 14
// baseline (472.013 us; speedup 1.0000x reference)
//
#include <hip/hip_runtime.h>
#include <hip/hip_bf16.h>

// Problem constants
#define T_TOKENS 4096      // B*S
#define DIM      1024
#define HID      4096
#define NE       8
#define CAP      4096      // max tokens per expert
#define SPLITS   4         // split-K factor for ffn2
#define KSP      (HID / SPLITS)   // 1024

typedef __attribute__((ext_vector_type(8))) short  bf16x8;
typedef __attribute__((ext_vector_type(4))) float  f32x4;
typedef __attribute__((ext_vector_type(4))) ushort u16x4;

__device__ static inline ushort f2bf(float f) {
    __hip_bfloat16 h = __float2bfloat16(f);
    return *(ushort*)&h;
}

// async global -> LDS, 16 bytes per lane. LDS dest = wave-uniform base +
// lane*16 (linear). Swizzle applied on the GLOBAL source address.
__device__ static inline void gll16(const void* g, void* l) {
    __builtin_amdgcn_global_load_lds(
        (const __attribute__((address_space(1))) void*)g,
        (__attribute__((address_space(3))) void*)l,
        16, 0, 0);
}

#define MFMA16(a, b, c) __builtin_amdgcn_mfma_f32_16x16x32_bf16((a), (b), (c), 0, 0, 0)

// ---------------------------------------------------------------------------
// Gate: logits -> top2 -> softmax -> per-expert token lists; also x -> bf16.
// tlist entry packs: tok (bits 0-11) | expert-slot k (bit 15).
// ---------------------------------------------------------------------------
__global__ __launch_bounds__(64) void gate_kernel(
    const float* __restrict__ x, const float* __restrict__ gw,
    const float* __restrict__ gb, __hip_bfloat16* __restrict__ xb,
    int* __restrict__ counts, int* __restrict__ tlist, float* __restrict__ plist)
{
    const int tok = blockIdx.x;
    const int l   = threadIdx.x;
    const float* xr = x + (size_t)tok * DIM;

    float part[NE];
#pragma unroll
    for (int e = 0; e < NE; e++) part[e] = 0.f;

#pragma unroll
    for (int i = 0; i < DIM / 64; i++) {
        int d = i * 64 + l;
        float xv = xr[d];
        xb[(size_t)tok * DIM + d] = __float2bfloat16(xv);
        const float4* g4 = (const float4*)(gw + (size_t)d * NE);
        float4 a = g4[0], b = g4[1];
        part[0] += xv * a.x; part[1] += xv * a.y;
        part[2] += xv * a.z; part[3] += xv * a.w;
        part[4] += xv * b.x; part[5] += xv * b.y;
        part[6] += xv * b.z; part[7] += xv * b.w;
    }
#pragma unroll
    for (int off = 32; off > 0; off >>= 1) {
#pragma unroll
        for (int e = 0; e < NE; e++) part[e] += __shfl_xor(part[e], off, 64);
    }
    if (l == 0) {
        float lg[NE];
#pragma unroll
        for (int e = 0; e < NE; e++) lg[e] = part[e] + gb[e];
        int i0 = 0;
#pragma unroll
        for (int e = 1; e < NE; e++) if (lg[e] > lg[i0]) i0 = e;   // lowest idx on tie
        int i1 = (i0 == 0) ? 1 : 0;
#pragma unroll
        for (int e = 0; e < NE; e++) if (e != i0 && lg[e] > lg[i1]) i1 = e;
        float t  = expf(lg[i1] - lg[i0]);
        float p0 = 1.f / (1.f + t);
        float p1 = t / (1.f + t);
        int pos0 = atomicAdd(&counts[i0], 1);
        tlist[i0 * CAP + pos0] = tok;              plist[i0 * CAP + pos0] = p0;
        int pos1 = atomicAdd(&counts[i1], 1);
        tlist[i1 * CAP + pos1] = tok | (1 << 15);  plist[i1 * CAP + pos1] = p1;
    }
}

// ---------------------------------------------------------------------------
// finalize: prefix-sum bases only (tasks are computed arithmetically).
// ---------------------------------------------------------------------------
__global__ void finalize_kernel(const int* __restrict__ counts, int* __restrict__ base)
{
    if (threadIdx.x == 0) {
        int acc = 0;
        for (int e = 0; e < NE; e++) { base[e] = acc; acc += counts[e]; }
        base[NE] = acc;
    }
}

// ---------------------------------------------------------------------------
// Transpose + f32->bf16 convert:  in [E][K][N] f32  ->  out [E][N][K] bf16
// ---------------------------------------------------------------------------
__global__ __launch_bounds__(256) void transpose_cvt64(
    const float* __restrict__ in, __hip_bfloat16* __restrict__ outp, int K, int N)
{
    __shared__ ushort tile[64][68];
    const int e  = blockIdx.z;
    const float* src = in + (size_t)e * K * N;
    ushort* dst = (ushort*)outp + (size_t)e * K * N;
    const int k0 = blockIdx.y * 64, n0 = blockIdx.x * 64;
    const int tid = threadIdx.x;

    const int rn4 = (tid & 15) * 4;
    const int rk  = tid >> 4;
#pragma unroll
    for (int p = 0; p < 4; p++) {
        int k = rk + p * 16;
        float4 v = *(const float4*)&src[(size_t)(k0 + k) * N + n0 + rn4];
        tile[k][rn4 + 0] = f2bf(v.x);
        tile[k][rn4 + 1] = f2bf(v.y);
        tile[k][rn4 + 2] = f2bf(v.z);
        tile[k][rn4 + 3] = f2bf(v.w);
    }
    __syncthreads();
    const int wk4 = (tid & 15) * 4;
    const int wn  = tid >> 4;
#pragma unroll
    for (int p = 0; p < 4; p++) {
        int n = wn + p * 16;
        u16x4 u;
        u[0] = tile[wk4 + 0][n];
        u[1] = tile[wk4 + 1][n];
        u[2] = tile[wk4 + 2][n];
        u[3] = tile[wk4 + 3][n];
        *(u16x4*)&dst[(size_t)(n0 + n) * K + k0 + wk4] = u;
    }
}

// ===========================================================================
// 256x128 8-phase grouped GEMM core (BM=256, BN=128, BK=64, 8 waves 4Mx2N,
// 64x64 output per wave). Halved from 256^2 (R13) to double task count and
// kill the task-quantization tail (R13: 2.25 tasks/CU, ceil 3 -> 33% idle;
// now exactly 4-5 tasks/CU per XCD).
// LDS 96 KiB: A slots (256x32) at (d*2+s)*8192, B slots (128x32) at
// 32768+(d*2+s)*4096. 6 gll16/tile (A:2+2, B:1+1); steady-state counted
// wait = vmcnt(5) (tile t+1 fully landed, tile t+2's 5 loads in flight).
// ===========================================================================

#define AOFFc(d,s) (((d)*2+(s))*8192)
#define BOFFc(d,s) (32768 + ((d)*2+(s))*4096)

#define MFMA_CL(nj0, nj1)                                                    \
    _Pragma("unroll")                                                        \
    for (int mi = 0; mi < 4; mi++) {                                         \
        acc[mi][nj0] = MFMA16(af[mi], bf##nj0, acc[mi][nj0]);                \
        acc[mi][nj1] = MFMA16(af[mi], bf##nj1, acc[mi][nj1]);                \
    }

#define GEMM_CORE(NT, srcA0, srcA1, srcB0)                                   \
    f32x4 acc[4][4];                                                         \
    _Pragma("unroll")                                                        \
    for (int i = 0; i < 4; i++)                                              \
        _Pragma("unroll")                                                    \
        for (int j = 0; j < 4; j++) acc[i][j] = (f32x4){0.f,0.f,0.f,0.f};    \
    const int a0 = (wr * 64 + lm) * 32 + rch;                                \
    const int b0 = (wc * 64 + lm) * 32 + rch;                                \
    /* prologue: tile0 (6 loads), tile1 first 5 (B-k1 comes at P0 of t=0) */ \
    gll16(srcA0,      &lds[AOFFc(0,0) + w*512]);                             \
    gll16(srcA1,      &lds[AOFFc(0,0) + 4096 + w*512]);                      \
    gll16(srcB0,      &lds[BOFFc(0,0) + w*512]);                             \
    gll16(srcA0 + 32, &lds[AOFFc(0,1) + w*512]);                             \
    gll16(srcA1 + 32, &lds[AOFFc(0,1) + 4096 + w*512]);                      \
    gll16(srcB0 + 32, &lds[BOFFc(0,1) + w*512]);                             \
    gll16(srcA0 + 64, &lds[AOFFc(1,0) + w*512]);                             \
    gll16(srcA1 + 64, &lds[AOFFc(1,0) + 4096 + w*512]);                      \
    gll16(srcB0 + 64, &lds[BOFFc(1,0) + w*512]);                             \
    gll16(srcA0 + 96, &lds[AOFFc(1,1) + w*512]);                             \
    gll16(srcA1 + 96, &lds[AOFFc(1,1) + 4096 + w*512]);                      \
    asm volatile("s_waitcnt vmcnt(5)" ::: "memory");                         \
    __builtin_amdgcn_s_barrier();                                            \
    _Pragma("unroll 1")                                                      \
    for (int t = 0; t < NT; t++) {                                           \
        const int d   = t & 1;                                               \
        const int aof  = d * 16384,       bof  = 32768 + d * 8192;           \
        const int bofN = 32768 + (d^1) * 8192;                               \
        bf16x8 af[4]; bf16x8 bf0, bf1, bf2, bf3;                             \
        /* P0: A ksub0 + B nj0,1 ksub0; stage (t+1).B-k1 */                  \
        _Pragma("unroll")                                                    \
        for (int mi = 0; mi < 4; mi++)                                       \
            af[mi] = *(const bf16x8*)&lds[aof + a0 + mi*512];                \
        bf0 = *(const bf16x8*)&lds[bof + b0];                                \
        bf1 = *(const bf16x8*)&lds[bof + b0 + 512];                          \
        if (t + 1 < NT) {                                                    \
            size_t ko = (size_t)(t+1)*64 + 32;                               \
            gll16(srcB0 + ko, &lds[bofN + 4096 + w*512]);                    \
        }                                                                    \
        __builtin_amdgcn_s_barrier();                                        \
        __builtin_amdgcn_s_setprio(1);                                       \
        MFMA_CL(0, 1)                                                        \
        __builtin_amdgcn_s_setprio(0);                                       \
        __builtin_amdgcn_s_barrier();                                        \
        /* P1: B nj2,3 ksub0; stage (t+2).A-k0 */                            \
        bf2 = *(const bf16x8*)&lds[bof + b0 + 1024];                         \
        bf3 = *(const bf16x8*)&lds[bof + b0 + 1536];                         \
        if (t + 2 < NT) {                                                    \
            size_t ko = (size_t)(t+2)*64;                                    \
            gll16(srcA0 + ko, &lds[aof + w*512]);                            \
            gll16(srcA1 + ko, &lds[aof + 4096 + w*512]);                     \
        }                                                                    \
        __builtin_amdgcn_s_barrier();                                        \
        __builtin_amdgcn_s_setprio(1);                                       \
        MFMA_CL(2, 3)                                                        \
        __builtin_amdgcn_s_setprio(0);                                       \
        __builtin_amdgcn_s_barrier();                                        \
        /* P2: A ksub1 + B nj0,1 ksub1; stage (t+2).B-k0 */                  \
        _Pragma("unroll")                                                    \
        for (int mi = 0; mi < 4; mi++)                                       \
            af[mi] = *(const bf16x8*)&lds[aof + 8192 + a0 + mi*512];         \
        bf0 = *(const bf16x8*)&lds[bof + 4096 + b0];                         \
        bf1 = *(const bf16x8*)&lds[bof + 4096 + b0 + 512];                   \
        if (t + 2 < NT) {                                                    \
            size_t ko = (size_t)(t+2)*64;                                    \
            gll16(srcB0 + ko, &lds[bof + w*512]);                            \
        }                                                                    \
        __builtin_amdgcn_s_barrier();                                        \
        __builtin_amdgcn_s_setprio(1);                                       \
        MFMA_CL(0, 1)                                                        \
        __builtin_amdgcn_s_setprio(0);                                       \
        __builtin_amdgcn_s_barrier();                                        \
        /* P3: B nj2,3 ksub1; stage (t+2).A-k1; counted wait */              \
        bf2 = *(const bf16x8*)&lds[bof + 4096 + b0 + 1024];                  \
        bf3 = *(const bf16x8*)&lds[bof + 4096 + b0 + 1536];                  \
        if (t + 2 < NT) {                                                    \
            size_t ko = (size_t)(t+2)*64 + 32;                               \
            gll16(srcA0 + ko, &lds[aof + 8192 + w*512]);                     \
            gll16(srcA1 + ko, &lds[aof + 8192 + 4096 + w*512]);              \
        }                                                                    \
        __builtin_amdgcn_s_barrier();                                        \
        __builtin_amdgcn_s_setprio(1);                                       \
        MFMA_CL(2, 3)                                                        \
        __builtin_amdgcn_s_setprio(0);                                       \
        if (t < NT - 2) { asm volatile("s_waitcnt vmcnt(5)" ::: "memory"); } \
        else            { asm volatile("s_waitcnt vmcnt(0)" ::: "memory"); } \
        __builtin_amdgcn_s_barrier();                                        \
    }

// Common per-thread index setup (8 waves, 4M x 2N over 256x128)
#define CORE_IDX                                                             \
    const int tid = threadIdx.x;                                             \
    const int l = tid & 63, w = tid >> 6;                                    \
    const int wr = w >> 1, wc = w & 1;                                       \
    const int lm = l & 15, kg = l >> 4;                                      \
    const int rch = (kg ^ ((lm >> 1) & 3)) * 8;                              \
    const int srow = tid >> 2;                                               \
    const int sch  = tid & 3;                                                \
    const int sc0  = (sch ^ ((srow >> 1) & 3)) * 8;

// ---------------------------------------------------------------------------
// FFN pass 1 (XCD-pinned, per-XCD ticket):  H = gelu( gather(xb)@w1t^T + b1 )
// Tasks: cb in 0..31 (128-wide), cb-major. tc*32 tasks/expert -> exactly
// 4 (tc=4) or 5 (tc=5) tasks per CU in the XCD: no intra-XCD ceiling waste.
// ---------------------------------------------------------------------------
__global__ __launch_bounds__(512, 1) void ffn1_kernel(
    const __hip_bfloat16* __restrict__ xb, const __hip_bfloat16* __restrict__ w1t,
    const float* __restrict__ b1, const int* __restrict__ counts,
    const int* __restrict__ base, const int* __restrict__ tlist,
    int* __restrict__ tickets, __hip_bfloat16* __restrict__ H)
{
    __shared__ __align__(16) ushort lds[49152];   // 96 KiB
    __shared__ int s_task;
    CORE_IDX
    const int e  = blockIdx.x & 7;      // expert == XCD
    const int ne = counts[e];
    const int tc = (ne + 255) >> 8;
    const int ntask = tc * 32;
    const int hb = base[e];
    if (tc == 0) return;

    for (;;) {
        __syncthreads();                // fences prev task's LDS use
        if (tid == 0) s_task = atomicAdd(&tickets[e], 1);
        __syncthreads();
        const int i = s_task;
        if (i >= ntask) break;
        const int cb = i / tc, rb = i - cb * tc;   // cb-major, cb 0..31

        const int rA0g = rb * 256 + srow;
        const int rA1g = rA0g + 128;
        const int tok0 = tlist[e * CAP + (rA0g < ne ? rA0g : ne - 1)] & 0xFFF;
        const int tok1 = tlist[e * CAP + (rA1g < ne ? rA1g : ne - 1)] & 0xFFF;
        const ushort* srcA0 = (const ushort*)xb + (size_t)tok0 * DIM + sc0;
        const ushort* srcA1 = (const ushort*)xb + (size_t)tok1 * DIM + sc0;
        const ushort* srcB0 = (const ushort*)w1t + ((size_t)e * HID + cb * 128 + srow) * DIM + sc0;

        GEMM_CORE(16, srcA0, srcA1, srcB0)

        // --- epilogue: bias + GELU -> LDS restage (256x128) -> 16B stores ---
#pragma unroll
        for (int nj = 0; nj < 4; nj++) {
            int col = wc * 64 + nj * 16 + lm;      // 0..127
            float bias = b1[e * HID + cb * 128 + col];
#pragma unroll
            for (int mi = 0; mi < 4; mi++) {
#pragma unroll
                for (int jj = 0; jj < 4; jj++) {
                    int row = wr * 64 + mi * 16 + kg * 4 + jj;
                    float vv = acc[mi][nj][jj] + bias;
                    vv = 0.5f * vv * (1.0f + erff(vv * 0.70710678118654752f));
                    lds[row * 128 + (col ^ ((row & 12) << 2))] = f2bf(vv);
                }
            }
        }
        __syncthreads();
#pragma unroll
        for (int pch = 0; pch < 8; pch++) {
            int c   = pch * 512 + tid;
            int row = c >> 4, seg = c & 15;
            int r   = rb * 256 + row;
            if (r < ne) {
                int pseg = seg ^ ((row & 12) >> 1);
                bf16x8 vv8 = *(const bf16x8*)&lds[row * 128 + pseg * 8];
                *(bf16x8*)((ushort*)H + (size_t)(hb + r) * HID + cb * 128 + seg * 8) = vv8;
            }
        }
    }
}

// ---------------------------------------------------------------------------
// FFN pass 2 (XCD-pinned, per-XCD ticket, split-K=4, no atomics):
// Tasks: c in 0..31, sp-major (sp = c>>3, cb = c&7) so concurrent CUs share
// 1-2 H sp-slices (2-4MB, L2-fit). Per-slot Y writes (slot = k*4+sp).
// ---------------------------------------------------------------------------
__global__ __launch_bounds__(512, 1) void ffn2_kernel(
    const __hip_bfloat16* __restrict__ H, const __hip_bfloat16* __restrict__ w2t,
    const float* __restrict__ b2, const int* __restrict__ counts,
    const int* __restrict__ base, const int* __restrict__ tlist,
    const float* __restrict__ plist, int* __restrict__ tickets,
    __hip_bfloat16* __restrict__ Y)
{
    __shared__ __align__(16) ushort lds[49152];   // 96 KiB
    __shared__ int s_task;
    CORE_IDX
    const int e  = blockIdx.x & 7;      // expert == XCD
    const int ne = counts[e];
    const int tc = (ne + 255) >> 8;
    const int ntask = tc * 32;
    const int hb = base[e];
    if (tc == 0) return;

    for (;;) {
        __syncthreads();
        if (tid == 0) s_task = atomicAdd(&tickets[NE + e], 1);
        __syncthreads();
        const int i = s_task;
        if (i >= ntask) break;
        const int c  = i / tc, rb = i - c * tc;    // c-major
        const int sp = c >> 3, cb = c & 7;         // sp-major

        const int rA0g = rb * 256 + srow;
        const int rA1g = rA0g + 128;
        const int hr0  = hb + (rA0g < ne ? rA0g : ne - 1);
        const int hr1  = hb + (rA1g < ne ? rA1g : ne - 1);
        const size_t ko0 = (size_t)sp * KSP;
        const ushort* srcA0 = (const ushort*)H + (size_t)hr0 * HID + ko0 + sc0;
        const ushort* srcA1 = (const ushort*)H + (size_t)hr1 * HID + ko0 + sc0;
        const ushort* srcB0 = (const ushort*)w2t + ((size_t)e * DIM + cb * 128 + srow) * HID + ko0 + sc0;

        GEMM_CORE(16, srcA0, srcA1, srcB0)

        // --- epilogue: (+bias)*p -> LDS restage (256x128) -> 16B stores ---
#pragma unroll
        for (int nj = 0; nj < 4; nj++) {
            int col = wc * 64 + nj * 16 + lm;
            float bias = (sp == 0) ? b2[e * DIM + cb * 128 + col] : 0.f;
#pragma unroll
            for (int mi = 0; mi < 4; mi++) {
#pragma unroll
                for (int jj = 0; jj < 4; jj++) {
                    int row = wr * 64 + mi * 16 + kg * 4 + jj;
                    int r   = rb * 256 + row;
                    float p = plist[e * CAP + (r < ne ? r : ne - 1)];
                    float vv = (acc[mi][nj][jj] + bias) * p;
                    lds[row * 128 + (col ^ ((row & 12) << 2))] = f2bf(vv);
                }
            }
        }
        __syncthreads();
#pragma unroll
        for (int pch = 0; pch < 8; pch++) {
            int cch = pch * 512 + tid;
            int row = cch >> 4, seg = cch & 15;
            int r   = rb * 256 + row;
            if (r < ne) {
                int tv  = tlist[e * CAP + r];
                int tok = tv & 0xFFF, kk = tv >> 15;
                int pseg = seg ^ ((row & 12) >> 1);
                bf16x8 vv8 = *(const bf16x8*)&lds[row * 128 + pseg * 8];
                *(bf16x8*)((ushort*)Y + ((size_t)(kk * 4 + sp) * T_TOKENS + tok) * DIM
                           + cb * 128 + seg * 8) = vv8;
            }
        }
    }
}

// ---------------------------------------------------------------------------
// Reduce: out[t][d] = sum of 8 slots (fixed order -> bitwise deterministic).
// ---------------------------------------------------------------------------
__global__ __launch_bounds__(256) void reduce_kernel(
    const __hip_bfloat16* __restrict__ Y, float* __restrict__ out)
{
    const size_t i = ((size_t)blockIdx.x * 256 + threadIdx.x) * 8;
    float s[8];
#pragma unroll
    for (int j = 0; j < 8; j++) s[j] = 0.f;
#pragma unroll
    for (int sl = 0; sl < 8; sl++) {
        bf16x8 v = *(const bf16x8*)((const ushort*)Y + (size_t)sl * T_TOKENS * DIM + i);
#pragma unroll
        for (int j = 0; j < 8; j++) {
            union { unsigned int ui; float f; } cv;
            cv.ui = ((unsigned int)(ushort)v[j]) << 16;
            s[j] += cv.f;
        }
    }
#pragma unroll
    for (int j = 0; j < 8; j++) out[i + j] = s[j];
}

// ---------------------------------------------------------------------------
extern "C" void kernel_launch(void* const* d_in, const int* in_sizes, int n_in,
                              void* d_out, int out_size, void* d_ws, size_t ws_size,
                              hipStream_t stream)
{
    const float* x  = (const float*)d_in[0];
    const float* gw = (const float*)d_in[1];
    const float* gb = (const float*)d_in[2];
    const float* w1 = (const float*)d_in[3];
    const float* b1 = (const float*)d_in[4];
    const float* w2 = (const float*)d_in[5];
    const float* b2 = (const float*)d_in[6];
    float* out = (float*)d_out;

    // workspace carve (bytes)
    char* ws = (char*)d_ws;
    __hip_bfloat16* w1t = (__hip_bfloat16*)(ws);                    // 67108864
    __hip_bfloat16* w2t = (__hip_bfloat16*)(ws + 67108864);         // 67108864
    __hip_bfloat16* Hb  = (__hip_bfloat16*)(ws + 134217728);        // 67108864
    __hip_bfloat16* xb  = (__hip_bfloat16*)(ws + 201326592);        // 8388608
    int*   tlist  = (int*)  (ws + 209715200);                       // 131072
    float* plist  = (float*)(ws + 209846272);                       // 131072
    int*   counts = (int*)  (ws + 209977344);                       // 64
    int*   basep  = (int*)  (ws + 209977408);                       // 64
    int*   tickets= (int*)  (ws + 209977472);                       // 64 (16 used)
    // Y slot buffer reuses w1t's 64 MB (dead after ffn1, stream-ordered).
    __hip_bfloat16* Y = (__hip_bfloat16*)(ws);

    hipMemsetAsync(counts, 0, 192, stream);   // counts+basep+tickets

    gate_kernel<<<T_TOKENS, 64, 0, stream>>>(x, gw, gb, xb, counts, tlist, plist);
    finalize_kernel<<<1, 64, 0, stream>>>(counts, basep);

    transpose_cvt64<<<dim3(HID / 64, DIM / 64, NE), 256, 0, stream>>>(w1, w1t, DIM, HID);
    transpose_cvt64<<<dim3(DIM / 64, HID / 64, NE), 256, 0, stream>>>(w2, w2t, HID, DIM);

    // XCD-pinned persistent grids: 1 block/CU, expert = blockIdx & 7,
    // per-XCD dynamic tickets
    ffn1_kernel<<<256, 512, 0, stream>>>(
        xb, w1t, b1, counts, basep, tlist, tickets, Hb);
    ffn2_kernel<<<256, 512, 0, stream>>>(
        Hb, w2t, b2, counts, basep, tlist, plist, tickets, Y);
    reduce_kernel<<<(T_TOKENS * DIM / 8) / 256, 256, 0, stream>>>(Y, out);
}

// Round 15
// 469.467 us; speedup vs baseline: 1.0054x; 1.0054x over previous
//
#include <hip/hip_runtime.h>
#include <hip/hip_bf16.h>

// Problem constants
#define T_TOKENS 4096      // B*S
#define DIM      1024
#define HID      4096
#define NE       8
#define CAP      4096      // max tokens per expert
#define SPLITS   4         // split-K factor for ffn2
#define KSP      (HID / SPLITS)   // 1024

typedef __attribute__((ext_vector_type(8))) short  bf16x8;
typedef __attribute__((ext_vector_type(4))) float  f32x4;
typedef __attribute__((ext_vector_type(4))) ushort u16x4;

__device__ static inline ushort f2bf(float f) {
    __hip_bfloat16 h = __float2bfloat16(f);
    return *(ushort*)&h;
}

// async global -> LDS, 16 bytes per lane. LDS dest = wave-uniform base +
// lane*16 (linear). Swizzle applied on the GLOBAL source address.
__device__ static inline void gll16(const void* g, void* l) {
    __builtin_amdgcn_global_load_lds(
        (const __attribute__((address_space(1))) void*)g,
        (__attribute__((address_space(3))) void*)l,
        16, 0, 0);
}

#define MFMA16(a, b, c) __builtin_amdgcn_mfma_f32_16x16x32_bf16((a), (b), (c), 0, 0, 0)

// ---------------------------------------------------------------------------
// Gate: logits -> top2 -> softmax -> per-expert token lists; also x -> bf16.
// tlist entry packs: tok (bits 0-11) | expert-slot k (bit 15).
// ---------------------------------------------------------------------------
__global__ __launch_bounds__(64) void gate_kernel(
    const float* __restrict__ x, const float* __restrict__ gw,
    const float* __restrict__ gb, __hip_bfloat16* __restrict__ xb,
    int* __restrict__ counts, int* __restrict__ tlist, float* __restrict__ plist)
{
    const int tok = blockIdx.x;
    const int l   = threadIdx.x;
    const float* xr = x + (size_t)tok * DIM;

    float part[NE];
#pragma unroll
    for (int e = 0; e < NE; e++) part[e] = 0.f;

#pragma unroll
    for (int i = 0; i < DIM / 64; i++) {
        int d = i * 64 + l;
        float xv = xr[d];
        xb[(size_t)tok * DIM + d] = __float2bfloat16(xv);
        const float4* g4 = (const float4*)(gw + (size_t)d * NE);
        float4 a = g4[0], b = g4[1];
        part[0] += xv * a.x; part[1] += xv * a.y;
        part[2] += xv * a.z; part[3] += xv * a.w;
        part[4] += xv * b.x; part[5] += xv * b.y;
        part[6] += xv * b.z; part[7] += xv * b.w;
    }
#pragma unroll
    for (int off = 32; off > 0; off >>= 1) {
#pragma unroll
        for (int e = 0; e < NE; e++) part[e] += __shfl_xor(part[e], off, 64);
    }
    if (l == 0) {
        float lg[NE];
#pragma unroll
        for (int e = 0; e < NE; e++) lg[e] = part[e] + gb[e];
        int i0 = 0;
#pragma unroll
        for (int e = 1; e < NE; e++) if (lg[e] > lg[i0]) i0 = e;   // lowest idx on tie
        int i1 = (i0 == 0) ? 1 : 0;
#pragma unroll
        for (int e = 0; e < NE; e++) if (e != i0 && lg[e] > lg[i1]) i1 = e;
        float t  = expf(lg[i1] - lg[i0]);
        float p0 = 1.f / (1.f + t);
        float p1 = t / (1.f + t);
        int pos0 = atomicAdd(&counts[i0], 1);
        tlist[i0 * CAP + pos0] = tok;              plist[i0 * CAP + pos0] = p0;
        int pos1 = atomicAdd(&counts[i1], 1);
        tlist[i1 * CAP + pos1] = tok | (1 << 15);  plist[i1 * CAP + pos1] = p1;
    }
}

// ---------------------------------------------------------------------------
// finalize: prefix-sum bases only.
// ---------------------------------------------------------------------------
__global__ void finalize_kernel(const int* __restrict__ counts, int* __restrict__ base)
{
    if (threadIdx.x == 0) {
        int acc = 0;
        for (int e = 0; e < NE; e++) { base[e] = acc; acc += counts[e]; }
        base[NE] = acc;
    }
}

// ---------------------------------------------------------------------------
// Transpose + f32->bf16 convert:  in [E][K][N] f32  ->  out [E][N][K] bf16
// ---------------------------------------------------------------------------
__global__ __launch_bounds__(256) void transpose_cvt64(
    const float* __restrict__ in, __hip_bfloat16* __restrict__ outp, int K, int N)
{
    __shared__ ushort tile[64][68];
    const int e  = blockIdx.z;
    const float* src = in + (size_t)e * K * N;
    ushort* dst = (ushort*)outp + (size_t)e * K * N;
    const int k0 = blockIdx.y * 64, n0 = blockIdx.x * 64;
    const int tid = threadIdx.x;

    const int rn4 = (tid & 15) * 4;
    const int rk  = tid >> 4;
#pragma unroll
    for (int p = 0; p < 4; p++) {
        int k = rk + p * 16;
        float4 v = *(const float4*)&src[(size_t)(k0 + k) * N + n0 + rn4];
        tile[k][rn4 + 0] = f2bf(v.x);
        tile[k][rn4 + 1] = f2bf(v.y);
        tile[k][rn4 + 2] = f2bf(v.z);
        tile[k][rn4 + 3] = f2bf(v.w);
    }
    __syncthreads();
    const int wk4 = (tid & 15) * 4;
    const int wn  = tid >> 4;
#pragma unroll
    for (int p = 0; p < 4; p++) {
        int n = wn + p * 16;
        u16x4 u;
        u[0] = tile[wk4 + 0][n];
        u[1] = tile[wk4 + 1][n];
        u[2] = tile[wk4 + 2][n];
        u[3] = tile[wk4 + 3][n];
        *(u16x4*)&dst[(size_t)(n0 + n) * K + k0 + wk4] = u;
    }
}

// ===========================================================================
// 128x128 8-phase grouped GEMM core (BM=BN=128, BK=64, 4 waves 2Mx2N,
// 64x64/wave). LDS 64 KiB -> TWO blocks per CU: when one block sits in its
// barrier/vmcnt drain the other block's MFMA waves fill the SIMDs (m114
// implicit overlap — the mechanism every prior 1-block/CU round lacked).
// Phase skeleton, stage-issue points, slot parity and vmcnt counts copied
// 1:1 from the verified 256^2 core; only sizes change (slot = 8KB,
// srcX1 = srcX0 + 16 rows, 2 loads/slot/thread as before).
// ===========================================================================

#define AOFFc(d,s) (((d)*2+(s))*4096)
#define BOFFc(d,s) (16384 + ((d)*2+(s))*4096)

#define MFMA_CL(nj0, nj1)                                                    \
    _Pragma("unroll")                                                        \
    for (int mi = 0; mi < 4; mi++) {                                         \
        acc[mi][nj0] = MFMA16(af[mi], bf##nj0, acc[mi][nj0]);                \
        acc[mi][nj1] = MFMA16(af[mi], bf##nj1, acc[mi][nj1]);                \
    }

#define GEMM_CORE(NT, srcA0, srcA1, srcB0, srcB1)                            \
    f32x4 acc[4][4];                                                         \
    _Pragma("unroll")                                                        \
    for (int i = 0; i < 4; i++)                                              \
        _Pragma("unroll")                                                    \
        for (int j = 0; j < 4; j++) acc[i][j] = (f32x4){0.f,0.f,0.f,0.f};    \
    const int a0 = (wr * 64 + lm) * 32 + rch;                                \
    const int b0 = (wc * 64 + lm) * 32 + rch;                                \
    gll16(srcA0,      &lds[AOFFc(0,0) + w*1024]);                            \
    gll16(srcA1,      &lds[AOFFc(0,0) + w*1024 + 512]);                      \
    gll16(srcB0,      &lds[BOFFc(0,0) + w*1024]);                            \
    gll16(srcB1,      &lds[BOFFc(0,0) + w*1024 + 512]);                      \
    gll16(srcA0 + 32, &lds[AOFFc(0,1) + w*1024]);                            \
    gll16(srcA1 + 32, &lds[AOFFc(0,1) + w*1024 + 512]);                      \
    gll16(srcB0 + 32, &lds[BOFFc(0,1) + w*1024]);                            \
    gll16(srcB1 + 32, &lds[BOFFc(0,1) + w*1024 + 512]);                      \
    asm volatile("s_waitcnt vmcnt(4)" ::: "memory");                         \
    gll16(srcA0 + 64, &lds[AOFFc(1,0) + w*1024]);                            \
    gll16(srcA1 + 64, &lds[AOFFc(1,0) + w*1024 + 512]);                      \
    gll16(srcB0 + 64, &lds[BOFFc(1,0) + w*1024]);                            \
    gll16(srcB1 + 64, &lds[BOFFc(1,0) + w*1024 + 512]);                      \
    gll16(srcA0 + 96, &lds[AOFFc(1,1) + w*1024]);                            \
    gll16(srcA1 + 96, &lds[AOFFc(1,1) + w*1024 + 512]);                      \
    asm volatile("s_waitcnt vmcnt(6)" ::: "memory");                         \
    __builtin_amdgcn_s_barrier();                                            \
    _Pragma("unroll 1")                                                      \
    for (int t = 0; t < NT; t++) {                                           \
        const int d   = t & 1;                                               \
        const int aof  = d * 8192,        bof  = 16384 + d * 8192;           \
        const int bofN = 16384 + (d^1) * 8192;                               \
        bf16x8 af[4]; bf16x8 bf0, bf1, bf2, bf3;                             \
        /* P0: A ksub0 + B nj0,1 ksub0; stage (t+1).B-k1 */                  \
        _Pragma("unroll")                                                    \
        for (int mi = 0; mi < 4; mi++)                                       \
            af[mi] = *(const bf16x8*)&lds[aof + a0 + mi*512];                \
        bf0 = *(const bf16x8*)&lds[bof + b0];                                \
        bf1 = *(const bf16x8*)&lds[bof + b0 + 512];                          \
        if (t + 1 < NT) {                                                    \
            size_t ko = (size_t)(t+1)*64 + 32;                               \
            gll16(srcB0 + ko, &lds[bofN + 4096 + w*1024]);                   \
            gll16(srcB1 + ko, &lds[bofN + 4096 + w*1024 + 512]);             \
        }                                                                    \
        __builtin_amdgcn_s_barrier();                                        \
        __builtin_amdgcn_s_setprio(1);                                       \
        MFMA_CL(0, 1)                                                        \
        __builtin_amdgcn_s_setprio(0);                                       \
        __builtin_amdgcn_s_barrier();                                        \
        /* P1: B nj2,3 ksub0; stage (t+2).A-k0 */                            \
        bf2 = *(const bf16x8*)&lds[bof + b0 + 1024];                         \
        bf3 = *(const bf16x8*)&lds[bof + b0 + 1536];                         \
        if (t + 2 < NT) {                                                    \
            size_t ko = (size_t)(t+2)*64;                                    \
            gll16(srcA0 + ko, &lds[aof + w*1024]);                           \
            gll16(srcA1 + ko, &lds[aof + w*1024 + 512]);                     \
        }                                                                    \
        __builtin_amdgcn_s_barrier();                                        \
        __builtin_amdgcn_s_setprio(1);                                       \
        MFMA_CL(2, 3)                                                        \
        __builtin_amdgcn_s_setprio(0);                                       \
        __builtin_amdgcn_s_barrier();                                        \
        /* P2: A ksub1 + B nj0,1 ksub1; stage (t+2).B-k0 */                  \
        _Pragma("unroll")                                                    \
        for (int mi = 0; mi < 4; mi++)                                       \
            af[mi] = *(const bf16x8*)&lds[aof + 4096 + a0 + mi*512];         \
        bf0 = *(const bf16x8*)&lds[bof + 4096 + b0];                         \
        bf1 = *(const bf16x8*)&lds[bof + 4096 + b0 + 512];                   \
        if (t + 2 < NT) {                                                    \
            size_t ko = (size_t)(t+2)*64;                                    \
            gll16(srcB0 + ko, &lds[bof + w*1024]);                           \
            gll16(srcB1 + ko, &lds[bof + w*1024 + 512]);                     \
        }                                                                    \
        __builtin_amdgcn_s_barrier();                                        \
        __builtin_amdgcn_s_setprio(1);                                       \
        MFMA_CL(0, 1)                                                        \
        __builtin_amdgcn_s_setprio(0);                                       \
        __builtin_amdgcn_s_barrier();                                        \
        /* P3: B nj2,3 ksub1; stage (t+2).A-k1; counted wait */              \
        bf2 = *(const bf16x8*)&lds[bof + 4096 + b0 + 1024];                  \
        bf3 = *(const bf16x8*)&lds[bof + 4096 + b0 + 1536];                  \
        if (t + 2 < NT) {                                                    \
            size_t ko = (size_t)(t+2)*64 + 32;                               \
            gll16(srcA0 + ko, &lds[aof + 4096 + w*1024]);                    \
            gll16(srcA1 + ko, &lds[aof + 4096 + w*1024 + 512]);              \
        }                                                                    \
        __builtin_amdgcn_s_barrier();                                        \
        __builtin_amdgcn_s_setprio(1);                                       \
        MFMA_CL(2, 3)                                                        \
        __builtin_amdgcn_s_setprio(0);                                       \
        if (t < NT - 2) { asm volatile("s_waitcnt vmcnt(6)" ::: "memory"); } \
        else            { asm volatile("s_waitcnt vmcnt(0)" ::: "memory"); } \
        __builtin_amdgcn_s_barrier();                                        \
    }

// Common per-thread index setup (4 waves, 2M x 2N over 128x128)
#define CORE_IDX                                                             \
    const int tid = threadIdx.x;                                             \
    const int l = tid & 63, w = tid >> 6;                                    \
    const int wr = w >> 1, wc = w & 1;                                       \
    const int lm = l & 15, kg = l >> 4;                                      \
    const int rch = (kg ^ ((lm >> 1) & 3)) * 8;                              \
    const int p0c  = w * 128 + l;                                            \
    const int srow = p0c >> 2;          /* row0 0..127 (row1 = +16) */       \
    const int sch  = p0c & 3;                                                \
    const int sc0  = (sch ^ ((srow >> 1) & 3)) * 8;

// ---------------------------------------------------------------------------
// FFN pass 1 (XCD-pinned, per-XCD ticket, 2 blocks/CU):
//   H = gelu( gather(xb) @ w1t^T + b1 )
// Tasks: cb 0..31 (128-wide N), cb-major; mt = ceil(ne/128) M-tiles.
// ---------------------------------------------------------------------------
__global__ __launch_bounds__(256, 2) void ffn1_kernel(
    const __hip_bfloat16* __restrict__ xb, const __hip_bfloat16* __restrict__ w1t,
    const float* __restrict__ b1, const int* __restrict__ counts,
    const int* __restrict__ base, const int* __restrict__ tlist,
    int* __restrict__ tickets, __hip_bfloat16* __restrict__ H)
{
    __shared__ __align__(16) ushort lds[32768];   // 64 KiB -> 2 blocks/CU
    __shared__ int s_task;
    CORE_IDX
    const int e  = blockIdx.x & 7;      // expert == XCD (64 workers/XCD)
    const int ne = counts[e];
    const int mt = (ne + 127) >> 7;
    const int ntask = mt * 32;
    const int hb = base[e];
    if (mt == 0) return;

    for (;;) {
        __syncthreads();                // fences prev task's LDS use
        if (tid == 0) s_task = atomicAdd(&tickets[e], 1);
        __syncthreads();
        const int i = s_task;
        if (i >= ntask) break;
        const int cb = i / mt, rb = i - cb * mt;   // cb-major, cb 0..31

        const int r0g = rb * 128 + srow;
        const int r1g = r0g + 16;
        const int tok0 = tlist[e * CAP + (r0g < ne ? r0g : ne - 1)] & 0xFFF;
        const int tok1 = tlist[e * CAP + (r1g < ne ? r1g : ne - 1)] & 0xFFF;
        const ushort* srcA0 = (const ushort*)xb + (size_t)tok0 * DIM + sc0;
        const ushort* srcA1 = (const ushort*)xb + (size_t)tok1 * DIM + sc0;
        const ushort* srcB0 = (const ushort*)w1t + ((size_t)e * HID + cb * 128 + srow) * DIM + sc0;
        const ushort* srcB1 = srcB0 + (size_t)16 * DIM;

        GEMM_CORE(16, srcA0, srcA1, srcB0, srcB1)

        // --- epilogue: bias + GELU -> LDS restage (128x128) -> 16B stores ---
#pragma unroll
        for (int nj = 0; nj < 4; nj++) {
            int col = wc * 64 + nj * 16 + lm;      // 0..127
            float bias = b1[e * HID + cb * 128 + col];
#pragma unroll
            for (int mi = 0; mi < 4; mi++) {
#pragma unroll
                for (int jj = 0; jj < 4; jj++) {
                    int row = wr * 64 + mi * 16 + kg * 4 + jj;
                    float vv = acc[mi][nj][jj] + bias;
                    vv = 0.5f * vv * (1.0f + erff(vv * 0.70710678118654752f));
                    lds[row * 128 + (col ^ ((row & 12) << 2))] = f2bf(vv);
                }
            }
        }
        __syncthreads();
#pragma unroll
        for (int pch = 0; pch < 8; pch++) {
            int c   = pch * 256 + tid;
            int row = c >> 4, seg = c & 15;
            int r   = rb * 128 + row;
            if (r < ne) {
                int pseg = seg ^ ((row & 12) >> 1);
                bf16x8 vv8 = *(const bf16x8*)&lds[row * 128 + pseg * 8];
                *(bf16x8*)((ushort*)H + (size_t)(hb + r) * HID + cb * 128 + seg * 8) = vv8;
            }
        }
    }
}

// ---------------------------------------------------------------------------
// FFN pass 2 (XCD-pinned, per-XCD ticket, 2 blocks/CU, split-K=4, no atomics):
// c in 0..31 sp-major (sp = c>>3, cb = c&7). Per-slot Y writes (kk*4+sp).
// ---------------------------------------------------------------------------
__global__ __launch_bounds__(256, 2) void ffn2_kernel(
    const __hip_bfloat16* __restrict__ H, const __hip_bfloat16* __restrict__ w2t,
    const float* __restrict__ b2, const int* __restrict__ counts,
    const int* __restrict__ base, const int* __restrict__ tlist,
    const float* __restrict__ plist, int* __restrict__ tickets,
    __hip_bfloat16* __restrict__ Y)
{
    __shared__ __align__(16) ushort lds[32768];   // 64 KiB -> 2 blocks/CU
    __shared__ int s_task;
    CORE_IDX
    const int e  = blockIdx.x & 7;      // expert == XCD
    const int ne = counts[e];
    const int mt = (ne + 127) >> 7;
    const int ntask = mt * 32;
    const int hb = base[e];
    if (mt == 0) return;

    for (;;) {
        __syncthreads();
        if (tid == 0) s_task = atomicAdd(&tickets[NE + e], 1);
        __syncthreads();
        const int i = s_task;
        if (i >= ntask) break;
        const int c  = i / mt, rb = i - c * mt;    // c-major
        const int sp = c >> 3, cb = c & 7;         // sp-major

        const int r0g = rb * 128 + srow;
        const int r1g = r0g + 16;
        const int hr0 = hb + (r0g < ne ? r0g : ne - 1);
        const int hr1 = hb + (r1g < ne ? r1g : ne - 1);
        const size_t ko0 = (size_t)sp * KSP;
        const ushort* srcA0 = (const ushort*)H + (size_t)hr0 * HID + ko0 + sc0;
        const ushort* srcA1 = (const ushort*)H + (size_t)hr1 * HID + ko0 + sc0;
        const ushort* srcB0 = (const ushort*)w2t + ((size_t)e * DIM + cb * 128 + srow) * HID + ko0 + sc0;
        const ushort* srcB1 = srcB0 + (size_t)16 * HID;

        GEMM_CORE(16, srcA0, srcA1, srcB0, srcB1)

        // --- epilogue: (+bias)*p -> LDS restage (128x128) -> 16B stores ---
#pragma unroll
        for (int nj = 0; nj < 4; nj++) {
            int col = wc * 64 + nj * 16 + lm;
            float bias = (sp == 0) ? b2[e * DIM + cb * 128 + col] : 0.f;
#pragma unroll
            for (int mi = 0; mi < 4; mi++) {
#pragma unroll
                for (int jj = 0; jj < 4; jj++) {
                    int row = wr * 64 + mi * 16 + kg * 4 + jj;
                    int r   = rb * 128 + row;
                    float p = plist[e * CAP + (r < ne ? r : ne - 1)];
                    float vv = (acc[mi][nj][jj] + bias) * p;
                    lds[row * 128 + (col ^ ((row & 12) << 2))] = f2bf(vv);
                }
            }
        }
        __syncthreads();
#pragma unroll
        for (int pch = 0; pch < 8; pch++) {
            int cch = pch * 256 + tid;
            int row = cch >> 4, seg = cch & 15;
            int r   = rb * 128 + row;
            if (r < ne) {
                int tv  = tlist[e * CAP + r];
                int tok = tv & 0xFFF, kk = tv >> 15;
                int pseg = seg ^ ((row & 12) >> 1);
                bf16x8 vv8 = *(const bf16x8*)&lds[row * 128 + pseg * 8];
                *(bf16x8*)((ushort*)Y + ((size_t)(kk * 4 + sp) * T_TOKENS + tok) * DIM
                           + cb * 128 + seg * 8) = vv8;
            }
        }
    }
}

// ---------------------------------------------------------------------------
// Reduce: out[t][d] = sum of 8 slots (fixed order -> bitwise deterministic).
// ---------------------------------------------------------------------------
__global__ __launch_bounds__(256) void reduce_kernel(
    const __hip_bfloat16* __restrict__ Y, float* __restrict__ out)
{
    const size_t i = ((size_t)blockIdx.x * 256 + threadIdx.x) * 8;
    float s[8];
#pragma unroll
    for (int j = 0; j < 8; j++) s[j] = 0.f;
#pragma unroll
    for (int sl = 0; sl < 8; sl++) {
        bf16x8 v = *(const bf16x8*)((const ushort*)Y + (size_t)sl * T_TOKENS * DIM + i);
#pragma unroll
        for (int j = 0; j < 8; j++) {
            union { unsigned int ui; float f; } cv;
            cv.ui = ((unsigned int)(ushort)v[j]) << 16;
            s[j] += cv.f;
        }
    }
#pragma unroll
    for (int j = 0; j < 8; j++) out[i + j] = s[j];
}

// ---------------------------------------------------------------------------
extern "C" void kernel_launch(void* const* d_in, const int* in_sizes, int n_in,
                              void* d_out, int out_size, void* d_ws, size_t ws_size,
                              hipStream_t stream)
{
    const float* x  = (const float*)d_in[0];
    const float* gw = (const float*)d_in[1];
    const float* gb = (const float*)d_in[2];
    const float* w1 = (const float*)d_in[3];
    const float* b1 = (const float*)d_in[4];
    const float* w2 = (const float*)d_in[5];
    const float* b2 = (const float*)d_in[6];
    float* out = (float*)d_out;

    // workspace carve (bytes)
    char* ws = (char*)d_ws;
    __hip_bfloat16* w1t = (__hip_bfloat16*)(ws);                    // 67108864
    __hip_bfloat16* w2t = (__hip_bfloat16*)(ws + 67108864);         // 67108864
    __hip_bfloat16* Hb  = (__hip_bfloat16*)(ws + 134217728);        // 67108864
    __hip_bfloat16* xb  = (__hip_bfloat16*)(ws + 201326592);        // 8388608
    int*   tlist  = (int*)  (ws + 209715200);                       // 131072
    float* plist  = (float*)(ws + 209846272);                       // 131072
    int*   counts = (int*)  (ws + 209977344);                       // 64
    int*   basep  = (int*)  (ws + 209977408);                       // 64
    int*   tickets= (int*)  (ws + 209977472);                       // 64 (16 used)
    // Y slot buffer reuses w1t's 64 MB (dead after ffn1, stream-ordered).
    __hip_bfloat16* Y = (__hip_bfloat16*)(ws);

    hipMemsetAsync(counts, 0, 192, stream);   // counts+basep+tickets

    gate_kernel<<<T_TOKENS, 64, 0, stream>>>(x, gw, gb, xb, counts, tlist, plist);
    finalize_kernel<<<1, 64, 0, stream>>>(counts, basep);

    transpose_cvt64<<<dim3(HID / 64, DIM / 64, NE), 256, 0, stream>>>(w1, w1t, DIM, HID);
    transpose_cvt64<<<dim3(DIM / 64, HID / 64, NE), 256, 0, stream>>>(w2, w2t, HID, DIM);

    // XCD-pinned persistent grids: 2 blocks/CU (512 blocks), e = blockIdx&7,
    // per-XCD dynamic tickets
    ffn1_kernel<<<512, 256, 0, stream>>>(
        xb, w1t, b1, counts, basep, tlist, tickets, Hb);
    ffn2_kernel<<<512, 256, 0, stream>>>(
        Hb, w2t, b2, counts, basep, tlist, plist, tickets, Y);
    reduce_kernel<<<(T_TOKENS * DIM / 8) / 256, 256, 0, stream>>>(Y, out);
}

// Round 16
// 435.552 us; speedup vs baseline: 1.0837x; 1.0779x over previous
//
#include <hip/hip_runtime.h>
#include <hip/hip_bf16.h>

// Problem constants
#define T_TOKENS 4096      // B*S
#define DIM      1024
#define HID      4096
#define NE       8
#define CAP      4096      // max tokens per expert
#define SPLITS   4         // split-K factor for ffn2
#define KSP      (HID / SPLITS)   // 1024

typedef __attribute__((ext_vector_type(8))) short  bf16x8;
typedef __attribute__((ext_vector_type(4))) float  f32x4;
typedef __attribute__((ext_vector_type(4))) ushort u16x4;

__device__ static inline ushort f2bf(float f) {
    __hip_bfloat16 h = __float2bfloat16(f);
    return *(ushort*)&h;
}

// async global -> LDS, 16 bytes per lane. LDS dest = wave-uniform base +
// lane*16 (linear). Swizzle applied on the GLOBAL source address.
__device__ static inline void gll16(const void* g, void* l) {
    __builtin_amdgcn_global_load_lds(
        (const __attribute__((address_space(1))) void*)g,
        (__attribute__((address_space(3))) void*)l,
        16, 0, 0);
}

#define MFMA16(a, b, c) __builtin_amdgcn_mfma_f32_16x16x32_bf16((a), (b), (c), 0, 0, 0)

// ---------------------------------------------------------------------------
// Gate: logits -> top2 -> softmax -> per-expert token lists; also x -> bf16.
// tlist entry packs: tok (bits 0-11) | expert-slot k (bit 15).
// ---------------------------------------------------------------------------
__global__ __launch_bounds__(64) void gate_kernel(
    const float* __restrict__ x, const float* __restrict__ gw,
    const float* __restrict__ gb, __hip_bfloat16* __restrict__ xb,
    int* __restrict__ counts, int* __restrict__ tlist, float* __restrict__ plist)
{
    const int tok = blockIdx.x;
    const int l   = threadIdx.x;
    const float* xr = x + (size_t)tok * DIM;

    float part[NE];
#pragma unroll
    for (int e = 0; e < NE; e++) part[e] = 0.f;

#pragma unroll
    for (int i = 0; i < DIM / 64; i++) {
        int d = i * 64 + l;
        float xv = xr[d];
        xb[(size_t)tok * DIM + d] = __float2bfloat16(xv);
        const float4* g4 = (const float4*)(gw + (size_t)d * NE);
        float4 a = g4[0], b = g4[1];
        part[0] += xv * a.x; part[1] += xv * a.y;
        part[2] += xv * a.z; part[3] += xv * a.w;
        part[4] += xv * b.x; part[5] += xv * b.y;
        part[6] += xv * b.z; part[7] += xv * b.w;
    }
#pragma unroll
    for (int off = 32; off > 0; off >>= 1) {
#pragma unroll
        for (int e = 0; e < NE; e++) part[e] += __shfl_xor(part[e], off, 64);
    }
    if (l == 0) {
        float lg[NE];
#pragma unroll
        for (int e = 0; e < NE; e++) lg[e] = part[e] + gb[e];
        int i0 = 0;
#pragma unroll
        for (int e = 1; e < NE; e++) if (lg[e] > lg[i0]) i0 = e;   // lowest idx on tie
        int i1 = (i0 == 0) ? 1 : 0;
#pragma unroll
        for (int e = 0; e < NE; e++) if (e != i0 && lg[e] > lg[i1]) i1 = e;
        float t  = expf(lg[i1] - lg[i0]);
        float p0 = 1.f / (1.f + t);
        float p1 = t / (1.f + t);
        int pos0 = atomicAdd(&counts[i0], 1);
        tlist[i0 * CAP + pos0] = tok;              plist[i0 * CAP + pos0] = p0;
        int pos1 = atomicAdd(&counts[i1], 1);
        tlist[i1 * CAP + pos1] = tok | (1 << 15);  plist[i1 * CAP + pos1] = p1;
    }
}

// ---------------------------------------------------------------------------
// finalize: prefix-sum bases only.
// ---------------------------------------------------------------------------
__global__ void finalize_kernel(const int* __restrict__ counts, int* __restrict__ base)
{
    if (threadIdx.x == 0) {
        int acc = 0;
        for (int e = 0; e < NE; e++) { base[e] = acc; acc += counts[e]; }
        base[NE] = acc;
    }
}

// ---------------------------------------------------------------------------
// Transpose + f32->bf16 convert:  in [E][K][N] f32  ->  out [E][N][K] bf16
// ---------------------------------------------------------------------------
__global__ __launch_bounds__(256) void transpose_cvt64(
    const float* __restrict__ in, __hip_bfloat16* __restrict__ outp, int K, int N)
{
    __shared__ ushort tile[64][68];
    const int e  = blockIdx.z;
    const float* src = in + (size_t)e * K * N;
    ushort* dst = (ushort*)outp + (size_t)e * K * N;
    const int k0 = blockIdx.y * 64, n0 = blockIdx.x * 64;
    const int tid = threadIdx.x;

    const int rn4 = (tid & 15) * 4;
    const int rk  = tid >> 4;
#pragma unroll
    for (int p = 0; p < 4; p++) {
        int k = rk + p * 16;
        float4 v = *(const float4*)&src[(size_t)(k0 + k) * N + n0 + rn4];
        tile[k][rn4 + 0] = f2bf(v.x);
        tile[k][rn4 + 1] = f2bf(v.y);
        tile[k][rn4 + 2] = f2bf(v.z);
        tile[k][rn4 + 3] = f2bf(v.w);
    }
    __syncthreads();
    const int wk4 = (tid & 15) * 4;
    const int wn  = tid >> 4;
#pragma unroll
    for (int p = 0; p < 4; p++) {
        int n = wn + p * 16;
        u16x4 u;
        u[0] = tile[wk4 + 0][n];
        u[1] = tile[wk4 + 1][n];
        u[2] = tile[wk4 + 2][n];
        u[3] = tile[wk4 + 3][n];
        *(u16x4*)&dst[(size_t)(n0 + n) * K + k0 + wk4] = u;
    }
}

// ===========================================================================
// m97-style 128x128 grouped GEMM core: BK=32, 4 waves (2Mx2N, 64x64/wave),
// double-buffered LDS (32 KiB total), ONE __syncthreads per K-step.
// __launch_bounds__(256,3) -> 3 blocks/CU co-resident: when one block sits
// in the barrier vmcnt drain, the other two keep the VMEM+MFMA pipes fed
// (m114 implicit overlap; m97 measured 22 B/cy/CU staging at this config vs
// 6-10 B/cy for every 1-2-block variant of rounds 4-15).
// LDS layout: lds[0..8191] = A dbuf (2x4096 ushorts), lds[8192..16383] = B.
// Slot interior: [128 rows][4 chunks of 8 bf16], chunk xor (row>>1)&3.
// ===========================================================================

#define MFMA_ALL                                                             \
    _Pragma("unroll")                                                        \
    for (int mi = 0; mi < 4; mi++)                                           \
        _Pragma("unroll")                                                    \
        for (int nj = 0; nj < 4; nj++)                                       \
            acc[mi][nj] = MFMA16(af[mi], bfr[nj], acc[mi][nj]);

#define GEMM_CORE(NK, srcA0, srcA1, srcB0, srcB1)                            \
    f32x4 acc[4][4];                                                         \
    _Pragma("unroll")                                                        \
    for (int i = 0; i < 4; i++)                                              \
        _Pragma("unroll")                                                    \
        for (int j = 0; j < 4; j++) acc[i][j] = (f32x4){0.f,0.f,0.f,0.f};    \
    gll16(srcA0, &lds[lo0]);        gll16(srcA1, &lds[lo1]);                 \
    gll16(srcB0, &lds[8192 + lo0]); gll16(srcB1, &lds[8192 + lo1]);          \
    int cur = 0;                                                             \
    _Pragma("unroll 1")                                                      \
    for (int ks = 0; ks < NK; ks++) {                                        \
        __syncthreads();                                                     \
        if (ks + 1 < NK) {                                                   \
            const int ko = (ks + 1) * 32;                                    \
            const int nb = (cur ^ 1) * 4096;                                 \
            gll16(srcA0 + ko, &lds[nb + lo0]);                               \
            gll16(srcA1 + ko, &lds[nb + lo1]);                               \
            gll16(srcB0 + ko, &lds[8192 + nb + lo0]);                        \
            gll16(srcB1 + ko, &lds[8192 + nb + lo1]);                        \
        }                                                                    \
        const int cb_ = cur * 4096;                                          \
        bf16x8 af[4], bfr[4];                                                \
        _Pragma("unroll")                                                    \
        for (int mi = 0; mi < 4; mi++) {                                     \
            int row = wr * 64 + mi * 16 + lm;                                \
            af[mi] = *(const bf16x8*)&lds[cb_ + row * 32 + rch];             \
        }                                                                    \
        _Pragma("unroll")                                                    \
        for (int nj = 0; nj < 4; nj++) {                                     \
            int row = wc * 64 + nj * 16 + lm;                                \
            bfr[nj] = *(const bf16x8*)&lds[8192 + cb_ + row * 32 + rch];     \
        }                                                                    \
        MFMA_ALL                                                             \
        cur ^= 1;                                                            \
    }

// Common per-thread index setup (4 waves, 2M x 2N over 128x128)
#define CORE_IDX                                                             \
    const int tid = threadIdx.x;                                             \
    const int l = tid & 63, w = tid >> 6;                                    \
    const int wr = w >> 1, wc = w & 1;                                       \
    const int lm = l & 15, kg = l >> 4;                                      \
    const int rch = (kg ^ ((lm >> 1) & 3)) * 8;                              \
    const int slot0 = w * 128 + l;                                           \
    const int slot1 = w * 128 + 64 + l;                                      \
    const int row0 = slot0 >> 2, row1 = slot1 >> 2;                          \
    const int ch0 = ((slot0 & 3) ^ ((row0 >> 1) & 3)) * 8;                   \
    const int ch1 = ((slot1 & 3) ^ ((row1 >> 1) & 3)) * 8;                   \
    const int lo0 = w * 1024;                                                \
    const int lo1 = w * 1024 + 512;

// ---------------------------------------------------------------------------
// FFN pass 1 (XCD-pinned, per-XCD ticket, 3 blocks/CU):
//   H = gelu( gather(xb) @ w1t^T + b1 )
// Tasks: cb 0..31 (BN=128), cb-major; mt = ceil(ne/128). 96 workers/XCD.
// ---------------------------------------------------------------------------
__global__ __launch_bounds__(256, 3) void ffn1_kernel(
    const __hip_bfloat16* __restrict__ xb, const __hip_bfloat16* __restrict__ w1t,
    const float* __restrict__ b1, const int* __restrict__ counts,
    const int* __restrict__ base, const int* __restrict__ tlist,
    int* __restrict__ tickets, __hip_bfloat16* __restrict__ H)
{
    __shared__ __align__(16) ushort lds[16384];   // 32 KiB -> 3 blocks/CU
    __shared__ int s_task;
    CORE_IDX
    const int e  = blockIdx.x & 7;      // expert == XCD (96 workers/XCD)
    const int ne = counts[e];
    const int mt = (ne + 127) >> 7;
    const int ntask = mt * 32;
    const int hb = base[e];
    if (mt == 0) return;

    for (;;) {
        __syncthreads();                // fences prev task's LDS use
        if (tid == 0) s_task = atomicAdd(&tickets[e], 1);
        __syncthreads();
        const int i = s_task;
        if (i >= ntask) break;
        const int cb = i / mt, rb = i - cb * mt;   // cb-major, cb 0..31

        const int r0g = rb * 128 + row0;
        const int r1g = rb * 128 + row1;
        const int tok0 = tlist[e * CAP + (r0g < ne ? r0g : ne - 1)] & 0xFFF;
        const int tok1 = tlist[e * CAP + (r1g < ne ? r1g : ne - 1)] & 0xFFF;
        const ushort* srcA0 = (const ushort*)xb + (size_t)tok0 * DIM + ch0;
        const ushort* srcA1 = (const ushort*)xb + (size_t)tok1 * DIM + ch1;
        const ushort* srcB0 = (const ushort*)w1t + ((size_t)e * HID + cb * 128 + row0) * DIM + ch0;
        const ushort* srcB1 = (const ushort*)w1t + ((size_t)e * HID + cb * 128 + row1) * DIM + ch1;

        GEMM_CORE(32, srcA0, srcA1, srcB0, srcB1)

        // --- epilogue: bias + GELU -> LDS restage (128x128) -> 16B stores ---
        __syncthreads();                // all LDS dead after final compute
#pragma unroll
        for (int nj = 0; nj < 4; nj++) {
            int col = wc * 64 + nj * 16 + lm;      // 0..127
            float bias = b1[e * HID + cb * 128 + col];
#pragma unroll
            for (int mi = 0; mi < 4; mi++) {
#pragma unroll
                for (int jj = 0; jj < 4; jj++) {
                    int row = wr * 64 + mi * 16 + kg * 4 + jj;
                    float vv = acc[mi][nj][jj] + bias;
                    vv = 0.5f * vv * (1.0f + erff(vv * 0.70710678118654752f));
                    lds[row * 128 + (col ^ ((row & 12) << 2))] = f2bf(vv);
                }
            }
        }
        __syncthreads();
#pragma unroll
        for (int pch = 0; pch < 8; pch++) {
            int c   = pch * 256 + tid;
            int row = c >> 4, seg = c & 15;
            int r   = rb * 128 + row;
            if (r < ne) {
                int pseg = seg ^ ((row & 12) >> 1);
                bf16x8 vv8 = *(const bf16x8*)&lds[row * 128 + pseg * 8];
                *(bf16x8*)((ushort*)H + (size_t)(hb + r) * HID + cb * 128 + seg * 8) = vv8;
            }
        }
    }
}

// ---------------------------------------------------------------------------
// FFN pass 2 (XCD-pinned, per-XCD ticket, 3 blocks/CU, split-K=4, no atomics):
// c 0..31 encodes (sp = c>>3, cb = c&7); per-slot Y writes (slot = kk*4+sp).
// ---------------------------------------------------------------------------
__global__ __launch_bounds__(256, 3) void ffn2_kernel(
    const __hip_bfloat16* __restrict__ H, const __hip_bfloat16* __restrict__ w2t,
    const float* __restrict__ b2, const int* __restrict__ counts,
    const int* __restrict__ base, const int* __restrict__ tlist,
    const float* __restrict__ plist, int* __restrict__ tickets,
    __hip_bfloat16* __restrict__ Y)
{
    __shared__ __align__(16) ushort lds[16384];   // 32 KiB -> 3 blocks/CU
    __shared__ int s_task;
    CORE_IDX
    const int e  = blockIdx.x & 7;      // expert == XCD
    const int ne = counts[e];
    const int mt = (ne + 127) >> 7;
    const int ntask = mt * 32;
    const int hb = base[e];
    if (mt == 0) return;

    for (;;) {
        __syncthreads();
        if (tid == 0) s_task = atomicAdd(&tickets[NE + e], 1);
        __syncthreads();
        const int i = s_task;
        if (i >= ntask) break;
        const int c  = i / mt, rb = i - c * mt;    // c-major
        const int sp = c >> 3, cb = c & 7;         // sp-major

        const int r0g = rb * 128 + row0;
        const int r1g = rb * 128 + row1;
        const int hr0 = hb + (r0g < ne ? r0g : ne - 1);
        const int hr1 = hb + (r1g < ne ? r1g : ne - 1);
        const size_t ko0 = (size_t)sp * KSP;
        const ushort* srcA0 = (const ushort*)H + (size_t)hr0 * HID + ko0 + ch0;
        const ushort* srcA1 = (const ushort*)H + (size_t)hr1 * HID + ko0 + ch1;
        const ushort* srcB0 = (const ushort*)w2t + ((size_t)e * DIM + cb * 128 + row0) * HID + ko0 + ch0;
        const ushort* srcB1 = (const ushort*)w2t + ((size_t)e * DIM + cb * 128 + row1) * HID + ko0 + ch1;

        GEMM_CORE(32, srcA0, srcA1, srcB0, srcB1)

        // --- epilogue: (+bias)*p -> LDS restage (128x128) -> 16B stores ---
        __syncthreads();
#pragma unroll
        for (int nj = 0; nj < 4; nj++) {
            int col = wc * 64 + nj * 16 + lm;
            float bias = (sp == 0) ? b2[e * DIM + cb * 128 + col] : 0.f;
#pragma unroll
            for (int mi = 0; mi < 4; mi++) {
#pragma unroll
                for (int jj = 0; jj < 4; jj++) {
                    int row = wr * 64 + mi * 16 + kg * 4 + jj;
                    int r   = rb * 128 + row;
                    float p = plist[e * CAP + (r < ne ? r : ne - 1)];
                    float vv = (acc[mi][nj][jj] + bias) * p;
                    lds[row * 128 + (col ^ ((row & 12) << 2))] = f2bf(vv);
                }
            }
        }
        __syncthreads();
#pragma unroll
        for (int pch = 0; pch < 8; pch++) {
            int cch = pch * 256 + tid;
            int row = cch >> 4, seg = cch & 15;
            int r   = rb * 128 + row;
            if (r < ne) {
                int tv  = tlist[e * CAP + r];
                int tok = tv & 0xFFF, kk = tv >> 15;
                int pseg = seg ^ ((row & 12) >> 1);
                bf16x8 vv8 = *(const bf16x8*)&lds[row * 128 + pseg * 8];
                *(bf16x8*)((ushort*)Y + ((size_t)(kk * 4 + sp) * T_TOKENS + tok) * DIM
                           + cb * 128 + seg * 8) = vv8;
            }
        }
    }
}

// ---------------------------------------------------------------------------
// Reduce: out[t][d] = sum of 8 slots (fixed order -> bitwise deterministic).
// ---------------------------------------------------------------------------
__global__ __launch_bounds__(256) void reduce_kernel(
    const __hip_bfloat16* __restrict__ Y, float* __restrict__ out)
{
    const size_t i = ((size_t)blockIdx.x * 256 + threadIdx.x) * 8;
    float s[8];
#pragma unroll
    for (int j = 0; j < 8; j++) s[j] = 0.f;
#pragma unroll
    for (int sl = 0; sl < 8; sl++) {
        bf16x8 v = *(const bf16x8*)((const ushort*)Y + (size_t)sl * T_TOKENS * DIM + i);
#pragma unroll
        for (int j = 0; j < 8; j++) {
            union { unsigned int ui; float f; } cv;
            cv.ui = ((unsigned int)(ushort)v[j]) << 16;
            s[j] += cv.f;
        }
    }
#pragma unroll
    for (int j = 0; j < 8; j++) out[i + j] = s[j];
}

// ---------------------------------------------------------------------------
extern "C" void kernel_launch(void* const* d_in, const int* in_sizes, int n_in,
                              void* d_out, int out_size, void* d_ws, size_t ws_size,
                              hipStream_t stream)
{
    const float* x  = (const float*)d_in[0];
    const float* gw = (const float*)d_in[1];
    const float* gb = (const float*)d_in[2];
    const float* w1 = (const float*)d_in[3];
    const float* b1 = (const float*)d_in[4];
    const float* w2 = (const float*)d_in[5];
    const float* b2 = (const float*)d_in[6];
    float* out = (float*)d_out;

    // workspace carve (bytes)
    char* ws = (char*)d_ws;
    __hip_bfloat16* w1t = (__hip_bfloat16*)(ws);                    // 67108864
    __hip_bfloat16* w2t = (__hip_bfloat16*)(ws + 67108864);         // 67108864
    __hip_bfloat16* Hb  = (__hip_bfloat16*)(ws + 134217728);        // 67108864
    __hip_bfloat16* xb  = (__hip_bfloat16*)(ws + 201326592);        // 8388608
    int*   tlist  = (int*)  (ws + 209715200);                       // 131072
    float* plist  = (float*)(ws + 209846272);                       // 131072
    int*   counts = (int*)  (ws + 209977344);                       // 64
    int*   basep  = (int*)  (ws + 209977408);                       // 64
    int*   tickets= (int*)  (ws + 209977472);                       // 64 (16 used)
    // Y slot buffer reuses w1t's 64 MB (dead after ffn1, stream-ordered).
    __hip_bfloat16* Y = (__hip_bfloat16*)(ws);

    hipMemsetAsync(counts, 0, 192, stream);   // counts+basep+tickets

    gate_kernel<<<T_TOKENS, 64, 0, stream>>>(x, gw, gb, xb, counts, tlist, plist);
    finalize_kernel<<<1, 64, 0, stream>>>(counts, basep);

    transpose_cvt64<<<dim3(HID / 64, DIM / 64, NE), 256, 0, stream>>>(w1, w1t, DIM, HID);
    transpose_cvt64<<<dim3(DIM / 64, HID / 64, NE), 256, 0, stream>>>(w2, w2t, HID, DIM);

    // XCD-pinned persistent grids: 3 blocks/CU (768 blocks), e = blockIdx&7,
    // per-XCD dynamic tickets
    ffn1_kernel<<<768, 256, 0, stream>>>(
        xb, w1t, b1, counts, basep, tlist, tickets, Hb);
    ffn2_kernel<<<768, 256, 0, stream>>>(
        Hb, w2t, b2, counts, basep, tlist, plist, tickets, Y);
    reduce_kernel<<<(T_TOKENS * DIM / 8) / 256, 256, 0, stream>>>(Y, out);
}